// Round 5
// baseline (235.327 us; speedup 1.0000x reference)
//
#include <hip/hip_runtime.h>

// out[b,c,l] = sum_{k=0..6} x[b,c,l+k-3] * w[b, c%G, k, l]   (zero-pad in l)
// B=8, C=256, L=8192, G=64, K=7.
// Latency-bound fix: VGPR-free MLP via global_load_lds staging.
// Block = (b,g): 4 waves = 4 channels of the group. Per tile of 1024 floats:
// stage w[7][1024] + x[4][1024] = 44 KB via 44 wave-calls (11/wave),
// triple-buffered LDS (132 KB), 2-deep prefetch, counted vmcnt(11),
// raw s_barrier (never __syncthreads -> would drain vmcnt to 0).

constexpr int Bn = 8, Cn = 256, Ln = 8192, Gn = 64, Kn = 7;
constexpr int BLOCK = 256;
constexpr int TL    = 1024;            // tile length in floats
constexpr int NT    = Ln / TL;         // 8 tiles
constexpr int XOFF  = Kn * TL;         // x region offset in buffer (floats)
constexpr int BUFF  = XOFF + 4 * TL;   // 11264 floats = 44 KiB per buffer
constexpr int NBUF  = 3;
constexpr int UPW   = 11;              // staging units (1 KB each) per wave

__device__ __forceinline__ void stage1k(const float* gsrc, float* ldst, int lane) {
    // wave-level: lane i copies 16B from gsrc+i*16 to ldst+i*16 (LDS dest linear)
    __builtin_amdgcn_global_load_lds(
        (const __attribute__((address_space(1))) void*)(gsrc + lane * 4),
        (__attribute__((address_space(3))) void*)ldst,
        16, 0, 0);
}

__device__ __forceinline__ float4 ld4s(const float* p) {
    return *reinterpret_cast<const float4*>(p);
}

__global__ __launch_bounds__(BLOCK) void ska1d_kernel(
    const float* __restrict__ x,
    const float* __restrict__ w,
    float* __restrict__ out)
{
    __shared__ float smem[NBUF * BUFF + 16];   // +16 floats: safe-pad for edge reads

    const int bid  = blockIdx.x;
    const int g    = bid & (Gn - 1);
    const int b    = bid >> 6;
    const int tid  = (int)threadIdx.x;
    const int wid  = tid >> 6;
    const int lane = tid & 63;

    const float* wg  = w + (size_t)(b * Gn + g) * Kn * Ln;
    const float* xg0 = x + (size_t)(b * Cn + g) * Ln;             // channel j=0 row
    const float* xgw = xg0 + (size_t)wid * Gn * Ln;               // this wave's channel
    float*       ogw = out + (size_t)(b * Cn + g) * Ln + (size_t)wid * Gn * Ln;

    // ---- staging: 44 units of 1KB; wave wid owns units [wid*11, wid*11+11) ----
    auto stage_tile = [&](int bufi, int t) {
        const int T0 = t * TL;
        float* buf = smem + bufi * BUFF;
#pragma unroll
        for (int i = 0; i < UPW; ++i) {
            const int u = wid * UPW + i;
            const float* src;
            int dst;
            if (u < 28) {                        // w units: k = u/4, quarter q = u%4
                const int k = u >> 2, q = u & 3;
                src = wg + (size_t)k * Ln + T0 + q * 256;
                dst = k * TL + q * 256;
            } else {                             // x units: j = (u-28)/4, q
                const int v = u - 28;
                const int j = v >> 2, q = v & 3;
                src = xg0 + (size_t)j * Gn * Ln + T0 + q * 256;
                dst = XOFF + j * TL + q * 256;
            }
            stage1k(src, buf + dst, lane);
        }
    };

    // ---- edge halo values from global (issued BEFORE stage burst each iter) ----
    auto edge_load = [&](int t, float4& eL, float4& eR) {
        const int T0 = t * TL;
        eL = make_float4(0.f, 0.f, 0.f, 0.f);
        eR = eL;
        if (lane == 0 && T0 > 0)
            eL = *reinterpret_cast<const float4*>(xgw + T0 - 4);
        if (lane == 63 && T0 + TL < Ln)
            eR = *reinterpret_cast<const float4*>(xgw + T0 + TL);
    };

    // ---- compute one tile from LDS ----
    auto compute_tile = [&](int bufi, int t, float4 eL, float4 eR) {
        const int T0 = t * TL;
        const float* wl = smem + bufi * BUFF;
        const float* xl = wl + XOFF + wid * TL;
#pragma unroll
        for (int s = 0; s < 4; ++s) {
            const int p = s * 256 + lane * 4;    // tile-local output base
            float4 W0 = ld4s(wl + 0 * TL + p);
            float4 W1 = ld4s(wl + 1 * TL + p);
            float4 W2 = ld4s(wl + 2 * TL + p);
            float4 W3 = ld4s(wl + 3 * TL + p);
            float4 W4 = ld4s(wl + 4 * TL + p);
            float4 W5 = ld4s(wl + 5 * TL + p);
            float4 W6 = ld4s(wl + 6 * TL + p);
            // x window [p-4, p+8); out-of-tile ends patched from eL/eR
            float4 va = (p >= 4)       ? ld4s(xl + p - 4) : eL;   // safe in-LDS addr
            float4 vb =                  ld4s(xl + p);
            float4 vc = (p + 8 <= TL)  ? ld4s(xl + p + 4) : eR;   // pad covers overrun

            float xs[12];
            xs[0] = va.x; xs[1] = va.y; xs[2]  = va.z; xs[3]  = va.w;
            xs[4] = vb.x; xs[5] = vb.y; xs[6]  = vb.z; xs[7]  = vb.w;
            xs[8] = vc.x; xs[9] = vc.y; xs[10] = vc.z; xs[11] = vc.w;

            const float4 Wv[7] = {W0, W1, W2, W3, W4, W5, W6};
            float4 o;
            float* opx = &o.x;
            const float* Wf = &Wv[0].x;
#pragma unroll
            for (int i = 0; i < 4; ++i) {
                float acc = 0.f;
#pragma unroll
                for (int k = 0; k < Kn; ++k)
                    acc = fmaf(xs[1 + i + k], Wf[k * 4 + i], acc);
                opx[i] = acc;
            }
            *reinterpret_cast<float4*>(ogw + T0 + p) = o;
        }
    };

    // ================= pipeline =================
    stage_tile(0, 0);
    stage_tile(1, 1);
    asm volatile("s_waitcnt vmcnt(11)" ::: "memory");   // tile 0 staged (this wave)
    __builtin_amdgcn_sched_barrier(0);
    __builtin_amdgcn_s_barrier();                       // all waves staged tile 0

    float4 eL, eR;
    for (int t = 0; t < NT - 2; ++t) {
        edge_load(t, eL, eR);                 // before stage burst: its use-wait
        __builtin_amdgcn_sched_barrier(0);    // won't drain the staging queue
        stage_tile((t + 2) % 3, t + 2);
        __builtin_amdgcn_sched_barrier(0);
        compute_tile(t % 3, t, eL, eR);
        // need tile t+1 complete; 11 newest (tile t+2 units) may stay in flight
        asm volatile("s_waitcnt vmcnt(11)" ::: "memory");
        __builtin_amdgcn_sched_barrier(0);
        __builtin_amdgcn_s_barrier();
    }
    edge_load(NT - 2, eL, eR);
    compute_tile((NT - 2) % 3, NT - 2, eL, eR);
    asm volatile("s_waitcnt vmcnt(0)" ::: "memory");    // drain last tile's staging
    __builtin_amdgcn_sched_barrier(0);
    __builtin_amdgcn_s_barrier();
    edge_load(NT - 1, eL, eR);
    compute_tile((NT - 1) % 3, NT - 1, eL, eR);
}

extern "C" void kernel_launch(void* const* d_in, const int* in_sizes, int n_in,
                              void* d_out, int out_size, void* d_ws, size_t ws_size,
                              hipStream_t stream)
{
    const float* x = (const float*)d_in[0];
    const float* w = (const float*)d_in[1];
    float* out     = (float*)d_out;

    const int grid = Bn * Gn;   // 512 blocks: one per (b, g)
    ska1d_kernel<<<grid, BLOCK, 0, stream>>>(x, w, out);
}

// Round 7
// 228.534 us; speedup vs baseline: 1.0297x; 1.0297x over previous
//
#include <hip/hip_runtime.h>

// out[b,c,l] = sum_{k=0..6} x[b,c,l+k-3] * w[b, c%G, k, l]   (zero-pad in l)
// B=8, C=256, L=8192, G=64, K=7.
// Round-2 structure (best: 79us) + NONTEMPORAL STORES via native clang
// vector type (float4 HIP_vector_type is rejected by the builtin).

constexpr int Bn   = 8;
constexpr int Cn   = 256;
constexpr int Ln   = 8192;
constexpr int Gn   = 64;
constexpr int Kn   = 7;
constexpr int CPG  = Cn / Gn;          // 4 channels share one weight group
constexpr int LPT  = 4;                // l positions per thread (float4)
constexpr int BLOCK = 256;
constexpr int TILE_L = BLOCK * LPT;    // 1024 l positions per block
constexpr int NTILE  = Ln / TILE_L;    // 8

typedef float floatx4 __attribute__((ext_vector_type(4)));

__global__ __launch_bounds__(BLOCK) void ska1d_kernel(
    const float* __restrict__ x,
    const float* __restrict__ w,
    float* __restrict__ out)
{
    const int bid   = blockIdx.x;
    const int ltile = bid % NTILE;
    const int g     = (bid / NTILE) % Gn;
    const int b     = bid / (NTILE * Gn);
    const int l0    = ltile * TILE_L + threadIdx.x * LPT;

    // ---- load w[b][g][k][l0..l0+3] for k=0..6, keep in registers ----
    const float* wbase = w + ((size_t)(b * Gn + g) * Kn) * Ln + l0;
    float wf[Kn][4];
#pragma unroll
    for (int k = 0; k < Kn; ++k) {
        float4 wv = *reinterpret_cast<const float4*>(wbase + (size_t)k * Ln);
        wf[k][0] = wv.x; wf[k][1] = wv.y; wf[k][2] = wv.z; wf[k][3] = wv.w;
    }

    // ---- for each of the 4 channels in this group ----
#pragma unroll
    for (int j = 0; j < CPG; ++j) {
        const int c = g + j * Gn;               // c % Gn == g
        const float* xrow = x + ((size_t)(b * Cn + c)) * Ln;

        // window x[l0-4 .. l0+7] via three aligned float4 loads (zero-pad edges)
        float4 va = (l0 >= 4)
                  ? *reinterpret_cast<const float4*>(xrow + l0 - 4)
                  : make_float4(0.f, 0.f, 0.f, 0.f);
        float4 vb = *reinterpret_cast<const float4*>(xrow + l0);
        float4 vc = (l0 + 4 < Ln)
                  ? *reinterpret_cast<const float4*>(xrow + l0 + 4)
                  : make_float4(0.f, 0.f, 0.f, 0.f);

        float xs[12];
        xs[0] = va.x; xs[1] = va.y; xs[2]  = va.z; xs[3]  = va.w;
        xs[4] = vb.x; xs[5] = vb.y; xs[6]  = vb.z; xs[7]  = vb.w;
        xs[8] = vc.x; xs[9] = vc.y; xs[10] = vc.z; xs[11] = vc.w;

        // out[l0+i] = sum_k x[l0+i+k-3] * w[k][l0+i] = sum_k xs[1+i+k] * wf[k][i]
        floatx4 o;
#pragma unroll
        for (int i = 0; i < 4; ++i) {
            float acc = 0.f;
#pragma unroll
            for (int k = 0; k < Kn; ++k)
                acc = fmaf(xs[1 + i + k], wf[k][i], acc);
            o[i] = acc;
        }
        // nontemporal: stream past L2/L3, don't evict the L3-resident inputs
        __builtin_nontemporal_store(
            o, reinterpret_cast<floatx4*>(out + ((size_t)(b * Cn + c)) * Ln + l0));
    }
}

extern "C" void kernel_launch(void* const* d_in, const int* in_sizes, int n_in,
                              void* d_out, int out_size, void* d_ws, size_t ws_size,
                              hipStream_t stream)
{
    const float* x = (const float*)d_in[0];
    const float* w = (const float*)d_in[1];
    float* out     = (float*)d_out;

    const int grid = Bn * Gn * NTILE;   // 4096 blocks
    ska1d_kernel<<<grid, BLOCK, 0, stream>>>(x, w, out);
}